// Round 4
// baseline (231.513 us; speedup 1.0000x reference)
//
#include <hip/hip_runtime.h>

// Problem constants: B=512, T=4096, C=7, H=3 ; N = 2,097,152 rows
constexpr long long N_ROWS = 512LL * 4096LL;
constexpr int BLOCK      = 64;     // ONE wave per block: per-wave-autonomous pipeline, zero barriers
constexpr int CHUNK_ROWS = 256;    // staging granularity: 256 rows * 7 floats = 7168 B per head
constexpr int CPB        = 4;      // chunks per block
constexpr int NBLOCKS    = (int)(N_ROWS / ((long long)CHUNK_ROWS * CPB));  // 2048

// Per-buffer LDS: 3 heads * 256 rows * 7 floats = 5376 floats = 21504 B.
// Double buffer = 43008 B/block -> 3 blocks/CU. Side data (labels/reward/mask)
// goes direct-to-register (48B lane stride, only 25% of bytes).
constexpr int BUFW = 5376;

__device__ __forceinline__ void async16(const float* g, float* l) {
    __builtin_amdgcn_global_load_lds(
        (const __attribute__((address_space(1))) unsigned int*)g,
        (__attribute__((address_space(3))) unsigned int*)l,
        16, 0, 0);
}

// R1 post-mortem: direct-to-register row loads (112B lane stride) inflate L1/TA
// transactions 7x AND the compiler serialized them into 32 VGPRs -> latency-bound
// at 1.6 TB/s. R0's coalesced LDS staging was killed by the vmcnt(0)+s_barrier
// drain at 2 blocks/CU. This kernel combines the fixes: coalesced global_load_lds
// staging (8 lines/instr, no VGPR cost) + per-wave double buffer with counted
// s_waitcnt vmcnt(21) and NO __syncthreads in the pipeline -> the next chunk's
// 21 loads stay in flight across every wait (vmcnt retires in issue order).
//
// R2 post-mortem: fused last-block reduce needs a zeroed arrival counter; the
// poisoned-workspace run failed. R3 (memset fix) died on infra. De-risked here:
// separate reduce dispatch (proven in R0/R1), no atomics, no workspace counter.
__global__ __launch_bounds__(BLOCK) void shortloss_main(
    const float* __restrict__ out0,
    const float* __restrict__ out1,
    const float* __restrict__ out2,
    const int*   __restrict__ labels,   // [N,3] int32
    const float* __restrict__ mask,     // [N]
    const float* __restrict__ reward,   // [N,3]
    float4*      __restrict__ partials) // [NBLOCKS]
{
    __shared__ float lds0[BUFW];
    __shared__ float lds1[BUFW];
    const int tid = threadIdx.x;
    const int c0  = blockIdx.x * CPB;   // first chunk index
    const float* outs[3] = {out0, out1, out2};

    // Whole-wave coalesced staging: per head 7168B = 7 x (64 lanes * 16B),
    // contiguous global -> contiguous LDS (identity lane mapping).
    auto stage = [&](int c, float* buf) {
        #pragma unroll
        for (int h = 0; h < 3; ++h) {
            const float* src = outs[h] + (size_t)c * 1792;   // 256 rows * 7
            float*       dst = buf + h * 1792;
            #pragma unroll
            for (int j = 0; j < 7; ++j)
                async16(src + j * 256 + 4 * (size_t)tid, dst + j * 256 + 4 * tid);
        }
    };

    // Side data for the 4 rows this lane computes in chunk c: rows c*256+4*tid..+3.
    auto side = [&](int c, int* lb, float* rw, float* mk) {
        const long long g = (long long)c * 64 + tid;         // quad-row index
        const int4*   lp = (const int4*)labels;
        const float4* rp = (const float4*)reward;
        #pragma unroll
        for (int j = 0; j < 3; ++j) {
            int4 t = lp[3 * g + j];
            lb[4*j+0] = t.x; lb[4*j+1] = t.y; lb[4*j+2] = t.z; lb[4*j+3] = t.w;
            float4 u = rp[3 * g + j];
            rw[4*j+0] = u.x; rw[4*j+1] = u.y; rw[4*j+2] = u.z; rw[4*j+3] = u.w;
        }
        float4 m = ((const float4*)mask)[g];
        mk[0] = m.x; mk[1] = m.y; mk[2] = m.z; mk[3] = m.w;
    };

    float L = 0.0f;
    int   C = 0, V = 0;

    // LDS reads: lane reads its 28 contiguous floats per head as 7 aligned
    // ds_read_b128 (word offset 28*tid: quad-bank (7*tid)%8 cycles all 8 ->
    // conflict-free). All o[] indices compile-time (no scratch spill).
    auto compute = [&](const float* buf, const int* lb, const float* rw, const float* mk) {
        float lsum[4] = {0.f, 0.f, 0.f, 0.f};
        int   ok[4]   = {1, 1, 1, 1};
        #pragma unroll
        for (int h = 0; h < 3; ++h) {
            float o[28];
            const float4* bp = (const float4*)(buf + h * 1792) + 7 * tid;
            #pragma unroll
            for (int j = 0; j < 7; ++j) {
                float4 t = bp[j];
                o[4*j+0] = t.x; o[4*j+1] = t.y; o[4*j+2] = t.z; o[4*j+3] = t.w;
            }
            #pragma unroll
            for (int i = 0; i < 4; ++i) {
                const int lbl = lb[3*i + h];
                const float* v = o + 7*i;

                // argmax, strict > (first-max tie-break, matches jnp.argmax)
                float best = v[0]; int bestc = 0;
                #pragma unroll
                for (int cc = 1; cc < 7; ++cc)
                    if (v[cc] > best) { best = v[cc]; bestc = cc; }

                // gather true-class prob via select chain (no dynamic reg index)
                float opv = v[0];
                #pragma unroll
                for (int cc = 1; cc < 7; ++cc)
                    opv = (lbl == cc) ? v[cc] : opv;

                lsum[i] += __logf(opv) * rw[3*i + h];
                ok[i]   &= (bestc == lbl) ? 1 : 0;
            }
        }
        #pragma unroll
        for (int i = 0; i < 4; ++i) {
            const bool valid = mk[i] < 0.5f;
            V += valid ? 1 : 0;
            L += valid ? lsum[i] : 0.0f;
            C += (valid && ok[i]) ? 1 : 0;
        }
    };

    int   lbA[12], lbB[12];
    float rwA[12], rwB[12], mkA[4], mkB[4];

    // ---- software pipeline, fully unrolled, barrier-free ----
    stage(c0 + 0, lds0);
    side (c0 + 0, lbA, rwA, mkA);
    stage(c0 + 1, lds1);
    asm volatile("s_waitcnt vmcnt(21)" ::: "memory");   // chunk0 staged (chunk1's 21 stay in flight)
    compute(lds0, lbA, rwA, mkA);

    side (c0 + 1, lbB, rwB, mkB);
    stage(c0 + 2, lds0);
    asm volatile("s_waitcnt vmcnt(21)" ::: "memory");   // chunk1 staged
    compute(lds1, lbB, rwB, mkB);

    side (c0 + 2, lbA, rwA, mkA);
    stage(c0 + 3, lds1);
    asm volatile("s_waitcnt vmcnt(21)" ::: "memory");   // chunk2 staged
    compute(lds0, lbA, rwA, mkA);

    side (c0 + 3, lbB, rwB, mkB);
    asm volatile("s_waitcnt vmcnt(7)" ::: "memory");    // chunk3 staged (side3 regs waited by compiler)
    compute(lds1, lbB, rwB, mkB);

    // ---- wave reduction (single wave per block) ----
    #pragma unroll
    for (int off = 32; off > 0; off >>= 1) {
        L += __shfl_down(L, off, 64);
        C += __shfl_down(C, off, 64);
        V += __shfl_down(V, off, 64);
    }
    if (tid == 0)
        partials[blockIdx.x] = make_float4(L, (float)C, (float)V, 0.0f);
}

__global__ __launch_bounds__(256) void shortloss_reduce(
    const float4* __restrict__ partials,
    float* __restrict__ out)
{
    float L = 0.0f, C = 0.0f, V = 0.0f;
    for (int i = threadIdx.x; i < NBLOCKS; i += 256) {
        float4 p = partials[i];
        L += p.x; C += p.y; V += p.z;
    }
    #pragma unroll
    for (int off = 32; off > 0; off >>= 1) {
        L += __shfl_down(L, off, 64);
        C += __shfl_down(C, off, 64);
        V += __shfl_down(V, off, 64);
    }
    __shared__ float sL[4], sC[4], sV[4];
    const int wave = threadIdx.x >> 6;
    if ((threadIdx.x & 63) == 0) { sL[wave] = L; sC[wave] = C; sV[wave] = V; }
    __syncthreads();
    if (threadIdx.x == 0) {
        float l = 0.0f, c = 0.0f, v = 0.0f;
        #pragma unroll
        for (int w = 0; w < 4; ++w) { l += sL[w]; c += sC[w]; v += sV[w]; }
        out[0] = -l / v;
        out[1] = c;
        out[2] = v;
    }
}

extern "C" void kernel_launch(void* const* d_in, const int* in_sizes, int n_in,
                              void* d_out, int out_size, void* d_ws, size_t ws_size,
                              hipStream_t stream) {
    const float* out0   = (const float*)d_in[0];
    const float* out1   = (const float*)d_in[1];
    const float* out2   = (const float*)d_in[2];
    const int*   labels = (const int*)  d_in[3];
    const float* mask   = (const float*)d_in[4];
    const float* reward = (const float*)d_in[5];

    float4* partials = (float4*)d_ws;   // 2048 * 16 B = 32 KB

    shortloss_main<<<NBLOCKS, BLOCK, 0, stream>>>(
        out0, out1, out2, labels, mask, reward, partials);
    shortloss_reduce<<<1, 256, 0, stream>>>(partials, (float*)d_out);
}

// Round 5
// 223.830 us; speedup vs baseline: 1.0343x; 1.0343x over previous
//
#include <hip/hip_runtime.h>

// Problem constants: B=512, T=4096, C=7, H=3 ; N = 2,097,152 rows
constexpr long long N_ROWS = 512LL * 4096LL;
constexpr int BLOCK = 256;                 // 4 waves
constexpr int RPT   = 4;                   // rows per thread (keeps all loads 16B-aligned)
constexpr int NBLOCKS = (int)(N_ROWS / ((long long)BLOCK * RPT));  // 2048

// R5: direct-to-register streaming with FORCED memory-level parallelism.
//
// R1 (same structure, loads inline with consumption) compiled to 32 VGPRs: the
// scheduler sank each float4 load next to its use -> ~2 loads in flight per
// wave -> queue-latency-bound at 4.4 B/cy/CU (43% of the m13 per-CU ceiling).
// R4 proved warm-L3 data doesn't speed this up (NaN-FETCH pass at identical
// dur): it's latency/MLP-bound, not BW-bound.
//
// Fix: hoist ALL 28 vector loads (21 outs + 3 labels + 3 reward + 1 mask) into
// registers BEFORE any consumption, fenced by sched_barrier(0) so the compiler
// cannot sink them. ~112 payload VGPRs -> ~12 waves/CU each with 28 loads in
// flight (~336 KB/CU outstanding). Compiler emits counted vmcnt waits, so
// compute on early loads overlaps tail-load latency. No LDS -> no barriers,
// no bank conflicts.
__global__ __launch_bounds__(BLOCK) void shortloss_main(
    const float* __restrict__ out0,
    const float* __restrict__ out1,
    const float* __restrict__ out2,
    const int*   __restrict__ labels,   // [N,3] int32
    const float* __restrict__ mask,     // [N]
    const float* __restrict__ reward,   // [N,3]
    float4*      __restrict__ partials) // [NBLOCKS]
{
    const int tid = threadIdx.x;
    const long long g = (long long)blockIdx.x * BLOCK + tid;   // quad-row index

    // ---------- issue ALL loads ----------
    const float4* p0 = (const float4*)out0 + 7 * g;
    const float4* p1 = (const float4*)out1 + 7 * g;
    const float4* p2 = (const float4*)out2 + 7 * g;
    float4 t[21];                      // 21 x dwordx4, constant-indexed -> registers
    #pragma unroll
    for (int j = 0; j < 7; ++j) t[j]      = p0[j];
    #pragma unroll
    for (int j = 0; j < 7; ++j) t[7 + j]  = p1[j];
    #pragma unroll
    for (int j = 0; j < 7; ++j) t[14 + j] = p2[j];

    int4 lv[3];
    float4 rv[3];
    {
        const int4*   lp = (const int4*)labels  + 3 * g;
        const float4* rp = (const float4*)reward + 3 * g;
        #pragma unroll
        for (int j = 0; j < 3; ++j) lv[j] = lp[j];
        #pragma unroll
        for (int j = 0; j < 3; ++j) rv[j] = rp[j];
    }
    float4 mkv = ((const float4*)mask)[g];

    // Fence: nothing below may be hoisted above / loads may not sink below.
    __builtin_amdgcn_sched_barrier(0);

    // ---------- unpack side data ----------
    const float mk[4] = {mkv.x, mkv.y, mkv.z, mkv.w};
    int lb[12];
    float rw[12];
    #pragma unroll
    for (int j = 0; j < 3; ++j) {
        lb[4*j+0] = lv[j].x; lb[4*j+1] = lv[j].y; lb[4*j+2] = lv[j].z; lb[4*j+3] = lv[j].w;
        rw[4*j+0] = rv[j].x; rw[4*j+1] = rv[j].y; rw[4*j+2] = rv[j].z; rw[4*j+3] = rv[j].w;
    }

    // ---------- per-head row math (register-local) ----------
    float lsum[4] = {0.f, 0.f, 0.f, 0.f};
    int   ok[4]   = {1, 1, 1, 1};
    #pragma unroll
    for (int h = 0; h < 3; ++h) {
        float o[28];
        #pragma unroll
        for (int j = 0; j < 7; ++j) {
            o[4*j+0] = t[7*h+j].x; o[4*j+1] = t[7*h+j].y;
            o[4*j+2] = t[7*h+j].z; o[4*j+3] = t[7*h+j].w;
        }
        #pragma unroll
        for (int i = 0; i < 4; ++i) {
            const int lbl = lb[3*i + h];
            const float* v = o + 7*i;

            // argmax, strict > (first-max tie-break, matches jnp.argmax)
            float best = v[0]; int bestc = 0;
            #pragma unroll
            for (int cc = 1; cc < 7; ++cc)
                if (v[cc] > best) { best = v[cc]; bestc = cc; }

            // gather true-class prob via select chain (no dynamic reg index)
            float opv = v[0];
            #pragma unroll
            for (int cc = 1; cc < 7; ++cc)
                opv = (lbl == cc) ? v[cc] : opv;

            lsum[i] += __logf(opv) * rw[3*i + h];
            ok[i]   &= (bestc == lbl) ? 1 : 0;
        }
    }

    float L = 0.0f;
    int   C = 0, V = 0;
    #pragma unroll
    for (int i = 0; i < 4; ++i) {
        const bool valid = mk[i] < 0.5f;
        V += valid ? 1 : 0;
        L += valid ? lsum[i] : 0.0f;
        C += (valid && ok[i]) ? 1 : 0;
    }

    // ---------- block reduction (proven path) ----------
    #pragma unroll
    for (int off = 32; off > 0; off >>= 1) {
        L += __shfl_down(L, off, 64);
        C += __shfl_down(C, off, 64);
        V += __shfl_down(V, off, 64);
    }
    __shared__ float sL[BLOCK / 64];
    __shared__ int   sC[BLOCK / 64], sV[BLOCK / 64];
    const int wave = tid >> 6;
    if ((tid & 63) == 0) { sL[wave] = L; sC[wave] = C; sV[wave] = V; }
    __syncthreads();
    if (tid == 0) {
        float l = 0.0f; int cc = 0, vv = 0;
        #pragma unroll
        for (int w = 0; w < BLOCK / 64; ++w) { l += sL[w]; cc += sC[w]; vv += sV[w]; }
        partials[blockIdx.x] = make_float4(l, (float)cc, (float)vv, 0.0f);
    }
}

__global__ __launch_bounds__(256) void shortloss_reduce(
    const float4* __restrict__ partials,
    float* __restrict__ out)
{
    float L = 0.0f, C = 0.0f, V = 0.0f;
    for (int i = threadIdx.x; i < NBLOCKS; i += 256) {
        float4 p = partials[i];
        L += p.x; C += p.y; V += p.z;
    }
    #pragma unroll
    for (int off = 32; off > 0; off >>= 1) {
        L += __shfl_down(L, off, 64);
        C += __shfl_down(C, off, 64);
        V += __shfl_down(V, off, 64);
    }
    __shared__ float sL[4], sC[4], sV[4];
    const int wave = threadIdx.x >> 6;
    if ((threadIdx.x & 63) == 0) { sL[wave] = L; sC[wave] = C; sV[wave] = V; }
    __syncthreads();
    if (threadIdx.x == 0) {
        float l = 0.0f, c = 0.0f, v = 0.0f;
        #pragma unroll
        for (int w = 0; w < 4; ++w) { l += sL[w]; c += sC[w]; v += sV[w]; }
        out[0] = -l / v;
        out[1] = c;
        out[2] = v;
    }
}

extern "C" void kernel_launch(void* const* d_in, const int* in_sizes, int n_in,
                              void* d_out, int out_size, void* d_ws, size_t ws_size,
                              hipStream_t stream) {
    const float* out0   = (const float*)d_in[0];
    const float* out1   = (const float*)d_in[1];
    const float* out2   = (const float*)d_in[2];
    const int*   labels = (const int*)  d_in[3];
    const float* mask   = (const float*)d_in[4];
    const float* reward = (const float*)d_in[5];

    float4* partials = (float4*)d_ws;   // 2048 * 16 B = 32 KB

    shortloss_main<<<NBLOCKS, BLOCK, 0, stream>>>(
        out0, out1, out2, labels, mask, reward, partials);
    shortloss_reduce<<<1, 256, 0, stream>>>(partials, (float*)d_out);
}